// Round 1
// baseline (78.449 us; speedup 1.0000x reference)
//
#include <hip/hip_runtime.h>
#include <hip/hip_bf16.h>

#define N 1024
#define D 8192
#define TM 128
#define NTROW 8
#define NUT 36
#define NC 8
#define KC 1024
#define BK 64
#define NSTEPS 16   // KC/BK
#define NPAIR 523776.0

typedef short short8 __attribute__((ext_vector_type(8)));
typedef float f32x4 __attribute__((ext_vector_type(4)));

__device__ inline unsigned short f2bf(float f) {
    __hip_bfloat16 h = __float2bfloat16(f);
    return __builtin_bit_cast(unsigned short, h);
}

__global__ __launch_bounds__(256, 2)
void gram_kernel(const float* __restrict__ pred, const float* __restrict__ tgt,
                 float* __restrict__ gram) {
    // XCD-aware swizzle: 576 blocks, groups of 36 tiles share (matrix,chunk) panels on one XCD
    int bid = blockIdx.x;
    int logical = (bid & 7) * 72 + (bid >> 3);
    int m = logical / 288;
    int rem = logical - m * 288;
    int chunk = rem / 36;
    int t = rem - chunk * 36;
    int ti = 0;
    while (t >= NTROW - ti) { t -= NTROW - ti; ++ti; }
    int tj = ti + t;
    const bool same = (ti == tj);

    const float* __restrict__ x = m ? tgt : pred;
    float* __restrict__ g = gram + m * (N * N);

    const int rowA0 = ti * TM, rowB0 = tj * TM;
    const int k0 = chunk * KC;

    __shared__ short lsA[TM * BK];
    __shared__ short lsB[TM * BK];

    const int tid = threadIdx.x;
    const int lane = tid & 63;
    const int wid = tid >> 6;
    const int wr = wid >> 1, wc = wid & 1;

    // staging: 4 slots/thread/tile, slot = 8 consecutive floats of a row
    const float* gA[4];
    const float* gB[4];
    int wby[4];
#pragma unroll
    for (int s = 0; s < 4; ++s) {
        int idx = s * 256 + tid;
        int r = idx >> 3, c8 = idx & 7;
        gA[s] = x + (size_t)(rowA0 + r) * D + k0 + c8 * 8;
        gB[s] = x + (size_t)(rowB0 + r) * D + k0 + c8 * 8;
        wby[s] = r * 128 + ((c8 * 16) ^ ((r & 7) << 4));   // XOR-swizzled LDS byte offset
    }

    float4 ra[4][2], rb[4][2];
    int koff = 0;
#pragma unroll
    for (int s = 0; s < 4; ++s) {
        const float4* p = (const float4*)(gA[s] + koff);
        ra[s][0] = p[0]; ra[s][1] = p[1];
        if (!same) { const float4* q = (const float4*)(gB[s] + koff); rb[s][0] = q[0]; rb[s][1] = q[1]; }
    }

    const int rbA = (wr * 64 + (lane & 15)) * 128;
    const int rbB = (wc * 64 + (lane & 15)) * 128;
    const int sw = (lane & 7) << 4;
    const int kx0 = ((lane >> 4) * 16) ^ sw;
    const int kx1 = (((lane >> 4) * 16) + 64) ^ sw;

    f32x4 zero = {0.f, 0.f, 0.f, 0.f};
    f32x4 acc[4][4];
#pragma unroll
    for (int mi = 0; mi < 4; ++mi)
#pragma unroll
        for (int ni = 0; ni < 4; ++ni) acc[mi][ni] = zero;

    for (int step = 0; step < NSTEPS; ++step) {
        __syncthreads();
        // write current staged regs to LDS (fp32 -> bf16)
#pragma unroll
        for (int s = 0; s < 4; ++s) {
            short8 v;
            v[0] = (short)f2bf(ra[s][0].x); v[1] = (short)f2bf(ra[s][0].y);
            v[2] = (short)f2bf(ra[s][0].z); v[3] = (short)f2bf(ra[s][0].w);
            v[4] = (short)f2bf(ra[s][1].x); v[5] = (short)f2bf(ra[s][1].y);
            v[6] = (short)f2bf(ra[s][1].z); v[7] = (short)f2bf(ra[s][1].w);
            *(short8*)((char*)lsA + wby[s]) = v;
            if (!same) {
                short8 w;
                w[0] = (short)f2bf(rb[s][0].x); w[1] = (short)f2bf(rb[s][0].y);
                w[2] = (short)f2bf(rb[s][0].z); w[3] = (short)f2bf(rb[s][0].w);
                w[4] = (short)f2bf(rb[s][1].x); w[5] = (short)f2bf(rb[s][1].y);
                w[6] = (short)f2bf(rb[s][1].z); w[7] = (short)f2bf(rb[s][1].w);
                *(short8*)((char*)lsB + wby[s]) = w;
            }
        }
        __syncthreads();
        // issue next-step global loads; latency hides under MFMA below
        if (step + 1 < NSTEPS) {
            koff += BK;
#pragma unroll
            for (int s = 0; s < 4; ++s) {
                const float4* p = (const float4*)(gA[s] + koff);
                ra[s][0] = p[0]; ra[s][1] = p[1];
                if (!same) { const float4* q = (const float4*)(gB[s] + koff); rb[s][0] = q[0]; rb[s][1] = q[1]; }
            }
        }
        const short* __restrict__ Bsrc = same ? lsA : lsB;
#pragma unroll
        for (int ks = 0; ks < 2; ++ks) {
            const int kx = ks ? kx1 : kx0;
            short8 af[4], bf[4];
#pragma unroll
            for (int mi = 0; mi < 4; ++mi)
                af[mi] = *(const short8*)((const char*)lsA + (rbA + mi * 2048 + kx));
#pragma unroll
            for (int ni = 0; ni < 4; ++ni)
                bf[ni] = *(const short8*)((const char*)Bsrc + (rbB + ni * 2048 + kx));
#pragma unroll
            for (int mi = 0; mi < 4; ++mi)
#pragma unroll
                for (int ni = 0; ni < 4; ++ni)
                    acc[mi][ni] = __builtin_amdgcn_mfma_f32_16x16x32_bf16(af[mi], bf[ni], acc[mi][ni], 0, 0, 0);
        }
    }

    // split-K combine via fp32 atomics (gram zeroed by memsetAsync each call)
#pragma unroll
    for (int mi = 0; mi < 4; ++mi)
#pragma unroll
        for (int ni = 0; ni < 4; ++ni)
#pragma unroll
            for (int r = 0; r < 4; ++r) {
                int gi = rowA0 + wr * 64 + mi * 16 + (lane >> 4) * 4 + r;
                int gj = rowB0 + wc * 64 + ni * 16 + (lane & 15);
                atomicAdd(&g[gi * N + gj], acc[mi][ni][r]);
            }
}

__global__ __launch_bounds__(256)
void loss_kernel(const float* __restrict__ gram, float* __restrict__ partial) {
    const float* __restrict__ gP = gram;
    const float* __restrict__ gT = gram + N * N;
    const int tid = threadIdx.x;
    const int base = blockIdx.x * 256 + tid;
    float local = 0.f;
#pragma unroll
    for (int s = 0; s < 4; ++s) {
        int lin = base + s * 262144;
        int i = lin >> 10, j = lin & 1023;
        if (j > i) {
            float dp = gP[i * N + i] + gP[j * N + j] - 2.f * gP[lin];
            float dt = gT[i * N + i] + gT[j * N + j] - 2.f * gT[lin];
            float c = sqrtf(fmaxf(dp, 0.f)) - sqrtf(fmaxf(dt, 0.f));
            local += c * c;
        }
    }
#pragma unroll
    for (int off = 32; off > 0; off >>= 1) local += __shfl_down(local, off);
    __shared__ float wsum[4];
    if ((tid & 63) == 0) wsum[tid >> 6] = local;
    __syncthreads();
    if (tid == 0) partial[blockIdx.x] = wsum[0] + wsum[1] + wsum[2] + wsum[3];
}

__global__ __launch_bounds__(256)
void finalize_kernel(const float* __restrict__ partial, float* __restrict__ out) {
    const int tid = threadIdx.x;
    double local = 0.0;
#pragma unroll
    for (int k = 0; k < 4; ++k) local += (double)partial[tid + k * 256];
#pragma unroll
    for (int off = 32; off > 0; off >>= 1) local += __shfl_down(local, off);
    __shared__ double wsum[4];
    if ((tid & 63) == 0) wsum[tid >> 6] = local;
    __syncthreads();
    if (tid == 0) out[0] = (float)((wsum[0] + wsum[1] + wsum[2] + wsum[3]) / NPAIR);
}

extern "C" void kernel_launch(void* const* d_in, const int* in_sizes, int n_in,
                              void* d_out, int out_size, void* d_ws, size_t ws_size,
                              hipStream_t stream) {
    const float* pred = (const float*)d_in[0];
    const float* tgt  = (const float*)d_in[1];
    float* ws = (float*)d_ws;
    float* gram = ws;                          // 2 * N*N floats = 8 MB
    float* partial = ws + 2 * (size_t)N * N;   // 1024 floats
    hipMemsetAsync(gram, 0, (size_t)2 * N * N * sizeof(float), stream);
    gram_kernel<<<576, 256, 0, stream>>>(pred, tgt, gram);
    loss_kernel<<<1024, 256, 0, stream>>>(gram, partial);
    finalize_kernel<<<1, 256, 0, stream>>>(partial, (float*)d_out);
}

// Round 2
// 66.091 us; speedup vs baseline: 1.1870x; 1.1870x over previous
//
#include <hip/hip_runtime.h>
#include <hip/hip_bf16.h>

#define D 8192
#define NPAIR 523776.0

typedef short short8 __attribute__((ext_vector_type(8)));
typedef float f32x4 __attribute__((ext_vector_type(4)));

__device__ __forceinline__ unsigned short f2bf(float f) {
    unsigned u = __builtin_bit_cast(unsigned, f);
    u += 0x7fffu + ((u >> 16) & 1u);      // round-to-nearest-even
    return (unsigned short)(u >> 16);
}

// 1024 blocks: bid = xcd(0..7) + 8*s, s in 0..127.
// m = xcd>>2 (matrix), xr = xcd&3.
// s < 112: off-diag tiles (28 pairs), chunk = 4*xr + s/28 (16 chunks of K=512)
// s >= 112: diag tiles (8), chunk = 2*xr + ((s-112)>>3) (8 chunks of K=1024)
__device__ __forceinline__ void decode_bid(int bid, int& m, int& ti, int& tj, int& k0, int& nsteps) {
    int x = bid & 7, s = bid >> 3;
    m = x >> 2;
    int xr = x & 3;
    if (s < 112) {
        int c = 4 * xr + s / 28;
        int tt = s % 28;
        int a = 0;
        while (tt >= 7 - a) { tt -= 7 - a; ++a; }
        ti = a; tj = a + 1 + tt;
        k0 = c * 512; nsteps = 16;
    } else {
        int r = s - 112;
        ti = tj = r & 7;
        int c = 2 * xr + (r >> 3);
        k0 = c * 1024; nsteps = 32;
    }
}
__device__ __forceinline__ int bid_off(int m, int tt, int c) {
    return (m * 4 + (c >> 2)) + (((c & 3) * 28 + tt) << 3);
}
__device__ __forceinline__ int bid_diag(int m, int dt, int c) {
    return (m * 4 + (c >> 1)) + ((112 + ((c & 1) << 3) + dt) << 3);
}

template<bool STORE>
__global__ __launch_bounds__(512, 4)
void gram_kernel(const float* __restrict__ pred, const float* __restrict__ tgt,
                 float* __restrict__ out) {
    int m, ti, tj, k0, nsteps;
    decode_bid(blockIdx.x, m, ti, tj, k0, nsteps);
    const bool same = (ti == tj);
    const float* __restrict__ x = m ? tgt : pred;

    __shared__ short lsA[2][4096];   // [128 rows][32 k] bf16, XOR-swizzled 16B slots
    __shared__ short lsB[2][4096];

    const int tid = threadIdx.x;
    const int lane = tid & 63;
    const int wid = tid >> 6;
    const int wr = wid >> 2, wc = wid & 3;   // 8 waves: 2 row-groups x 4 col-groups

    // staging: one 8-float slot per thread per matrix: row = tid>>2, k-group = tid&3
    const int srow = tid >> 2, sc8 = tid & 3;
    const float* __restrict__ gA = x + (size_t)(ti * 128 + srow) * D + k0 + sc8 * 8;
    const float* __restrict__ gB = x + (size_t)(tj * 128 + srow) * D + k0 + sc8 * 8;
    const int wby = srow * 64 + ((sc8 ^ ((srow >> 1) & 3)) << 4);  // swizzled LDS byte offset

    // fragment read offsets (swizzle matches wby; mi*16 rows doesn't change (row>>1)&3)
    const int rbA = (wr * 64 + (lane & 15)) * 64;
    const int rbB = (wc * 32 + (lane & 15)) * 64;
    const int kby = (((lane >> 4) ^ (((lane & 15) >> 1) & 3)) << 4);

    f32x4 zero = {0.f, 0.f, 0.f, 0.f};
    f32x4 acc[4][2];
#pragma unroll
    for (int mi = 0; mi < 4; ++mi) { acc[mi][0] = zero; acc[mi][1] = zero; }

    float4 ra0, ra1, rb0, rb1;
    // prologue: load step0, write buf0, load step1
    { const float4* p = (const float4*)gA; ra0 = p[0]; ra1 = p[1];
      if (!same) { const float4* q = (const float4*)gB; rb0 = q[0]; rb1 = q[1]; } }
    {
        short8 v;
        v[0]=(short)f2bf(ra0.x); v[1]=(short)f2bf(ra0.y); v[2]=(short)f2bf(ra0.z); v[3]=(short)f2bf(ra0.w);
        v[4]=(short)f2bf(ra1.x); v[5]=(short)f2bf(ra1.y); v[6]=(short)f2bf(ra1.z); v[7]=(short)f2bf(ra1.w);
        *(short8*)((char*)lsA[0] + wby) = v;
        if (!same) {
            short8 w;
            w[0]=(short)f2bf(rb0.x); w[1]=(short)f2bf(rb0.y); w[2]=(short)f2bf(rb0.z); w[3]=(short)f2bf(rb0.w);
            w[4]=(short)f2bf(rb1.x); w[5]=(short)f2bf(rb1.y); w[6]=(short)f2bf(rb1.z); w[7]=(short)f2bf(rb1.w);
            *(short8*)((char*)lsB[0] + wby) = w;
        }
    }
    { const float4* p = (const float4*)(gA + 32); ra0 = p[0]; ra1 = p[1];
      if (!same) { const float4* q = (const float4*)(gB + 32); rb0 = q[0]; rb1 = q[1]; } }
    asm volatile("s_waitcnt lgkmcnt(0)" ::: "memory");
    __builtin_amdgcn_s_barrier();

    for (int step = 0; step < nsteps; ++step) {
        const int cur = step & 1;
        const short* __restrict__ bufA = lsA[cur];
        const short* __restrict__ bufB = same ? lsA[cur] : lsB[cur];
        if (step + 1 < nsteps) {
            const int nxt = cur ^ 1;
            short8 v;
            v[0]=(short)f2bf(ra0.x); v[1]=(short)f2bf(ra0.y); v[2]=(short)f2bf(ra0.z); v[3]=(short)f2bf(ra0.w);
            v[4]=(short)f2bf(ra1.x); v[5]=(short)f2bf(ra1.y); v[6]=(short)f2bf(ra1.z); v[7]=(short)f2bf(ra1.w);
            *(short8*)((char*)lsA[nxt] + wby) = v;
            if (!same) {
                short8 w;
                w[0]=(short)f2bf(rb0.x); w[1]=(short)f2bf(rb0.y); w[2]=(short)f2bf(rb0.z); w[3]=(short)f2bf(rb0.w);
                w[4]=(short)f2bf(rb1.x); w[5]=(short)f2bf(rb1.y); w[6]=(short)f2bf(rb1.z); w[7]=(short)f2bf(rb1.w);
                *(short8*)((char*)lsB[nxt] + wby) = w;
            }
            if (step + 2 < nsteps) {   // prefetch; stays in flight across the raw barrier
                const float4* p = (const float4*)(gA + (step + 2) * 32);
                ra0 = p[0]; ra1 = p[1];
                if (!same) { const float4* q = (const float4*)(gB + (step + 2) * 32); rb0 = q[0]; rb1 = q[1]; }
            }
        }
        short8 bf0 = *(const short8*)((const char*)bufB + (rbB + kby));
        short8 bf1 = *(const short8*)((const char*)bufB + (rbB + 1024 + kby));
#pragma unroll
        for (int mi = 0; mi < 4; ++mi) {
            short8 af = *(const short8*)((const char*)bufA + (rbA + mi * 1024 + kby));
            acc[mi][0] = __builtin_amdgcn_mfma_f32_16x16x32_bf16(af, bf0, acc[mi][0], 0, 0, 0);
            acc[mi][1] = __builtin_amdgcn_mfma_f32_16x16x32_bf16(af, bf1, acc[mi][1], 0, 0, 0);
        }
        asm volatile("s_waitcnt lgkmcnt(0)" ::: "memory");
        __builtin_amdgcn_s_barrier();
    }

    if (STORE) {
        float* __restrict__ dst = out + (size_t)blockIdx.x * 16384;
#pragma unroll
        for (int mi = 0; mi < 4; ++mi)
#pragma unroll
            for (int ni = 0; ni < 2; ++ni)
#pragma unroll
                for (int r = 0; r < 4; ++r) {
                    int li = wr * 64 + mi * 16 + (lane >> 4) * 4 + r;
                    int lj = wc * 32 + ni * 16 + (lane & 15);
                    dst[li * 128 + lj] = acc[mi][ni][r];
                }
    } else {
        float* __restrict__ g = out + (size_t)m * (1024 * 1024);
#pragma unroll
        for (int mi = 0; mi < 4; ++mi)
#pragma unroll
            for (int ni = 0; ni < 2; ++ni)
#pragma unroll
                for (int r = 0; r < 4; ++r) {
                    int gi = ti * 128 + wr * 64 + mi * 16 + (lane >> 4) * 4 + r;
                    int gj = tj * 128 + wc * 32 + ni * 16 + (lane & 15);
                    atomicAdd(&g[gi * 1024 + gj], acc[mi][ni][r]);
                }
    }
}

__global__ __launch_bounds__(256)
void norms_kernel(const float* __restrict__ part, float* __restrict__ norms) {
    int id = blockIdx.x * 256 + threadIdx.x;   // 0..2047: m = id>>10, i = id&1023
    int m = id >> 10, i = id & 1023;
    int dt = i >> 7, li = i & 127;
    float s = 0.f;
#pragma unroll
    for (int c = 0; c < 8; ++c)
        s += part[(size_t)bid_diag(m, dt, c) * 16384 + li * 129];
    norms[id] = s;
}

__global__ __launch_bounds__(256)
void loss_store_kernel(const float* __restrict__ part, const float* __restrict__ norms,
                       float* __restrict__ partial) {
    const int tid = threadIdx.x;
    const int base = blockIdx.x * 256 + tid;
    float local = 0.f;
#pragma unroll
    for (int s = 0; s < 4; ++s) {
        int lin = base + s * 262144;
        int i = lin >> 10, j = lin & 1023;
        if (j > i) {
            int ti = i >> 7, tj = j >> 7;
            int el = (i & 127) * 128 + (j & 127);
            float gp = 0.f, gt = 0.f;
            if (ti == tj) {
#pragma unroll
                for (int c = 0; c < 8; ++c) {
                    gp += part[(size_t)bid_diag(0, ti, c) * 16384 + el];
                    gt += part[(size_t)bid_diag(1, ti, c) * 16384 + el];
                }
            } else {
                int tt = 7 * ti - (ti * (ti - 1)) / 2 + (tj - ti - 1);
#pragma unroll
                for (int c = 0; c < 16; ++c) {
                    gp += part[(size_t)bid_off(0, tt, c) * 16384 + el];
                    gt += part[(size_t)bid_off(1, tt, c) * 16384 + el];
                }
            }
            float dp = norms[i] + norms[j] - 2.f * gp;
            float dt_ = norms[1024 + i] + norms[1024 + j] - 2.f * gt;
            float c2 = sqrtf(fmaxf(dp, 0.f)) - sqrtf(fmaxf(dt_, 0.f));
            local += c2 * c2;
        }
    }
#pragma unroll
    for (int off = 32; off > 0; off >>= 1) local += __shfl_down(local, off);
    __shared__ float wsum[4];
    if ((tid & 63) == 0) wsum[tid >> 6] = local;
    __syncthreads();
    if (tid == 0) partial[blockIdx.x] = wsum[0] + wsum[1] + wsum[2] + wsum[3];
}

// fallback loss (atomic path): reads dense gram[2][1024][1024]
__global__ __launch_bounds__(256)
void loss_atomic_kernel(const float* __restrict__ gram, float* __restrict__ partial) {
    const float* __restrict__ gP = gram;
    const float* __restrict__ gT = gram + 1024 * 1024;
    const int tid = threadIdx.x;
    const int base = blockIdx.x * 256 + tid;
    float local = 0.f;
#pragma unroll
    for (int s = 0; s < 4; ++s) {
        int lin = base + s * 262144;
        int i = lin >> 10, j = lin & 1023;
        if (j > i) {
            float dp = gP[i * 1024 + i] + gP[j * 1024 + j] - 2.f * gP[lin];
            float dt = gT[i * 1024 + i] + gT[j * 1024 + j] - 2.f * gT[lin];
            float c = sqrtf(fmaxf(dp, 0.f)) - sqrtf(fmaxf(dt, 0.f));
            local += c * c;
        }
    }
#pragma unroll
    for (int off = 32; off > 0; off >>= 1) local += __shfl_down(local, off);
    __shared__ float wsum[4];
    if ((tid & 63) == 0) wsum[tid >> 6] = local;
    __syncthreads();
    if (tid == 0) partial[blockIdx.x] = wsum[0] + wsum[1] + wsum[2] + wsum[3];
}

__global__ __launch_bounds__(256)
void finalize_kernel(const float* __restrict__ partial, float* __restrict__ out) {
    const int tid = threadIdx.x;
    double local = 0.0;
#pragma unroll
    for (int k = 0; k < 4; ++k) local += (double)partial[tid + k * 256];
#pragma unroll
    for (int off = 32; off > 0; off >>= 1) local += __shfl_down(local, off);
    __shared__ double wsum[4];
    if ((tid & 63) == 0) wsum[tid >> 6] = local;
    __syncthreads();
    if (tid == 0) out[0] = (float)((wsum[0] + wsum[1] + wsum[2] + wsum[3]) / NPAIR);
}

extern "C" void kernel_launch(void* const* d_in, const int* in_sizes, int n_in,
                              void* d_out, int out_size, void* d_ws, size_t ws_size,
                              hipStream_t stream) {
    const float* pred = (const float*)d_in[0];
    const float* tgt  = (const float*)d_in[1];
    float* ws = (float*)d_ws;
    const size_t need = (size_t)1024 * 16384 * 4 + (2048 + 1024) * 4;
    if (ws_size >= need) {
        float* part    = ws;                           // 1024 x 16384 f32 = 67 MB
        float* norms   = ws + (size_t)1024 * 16384;    // 2048 f32
        float* partial = norms + 2048;                 // 1024 f32
        gram_kernel<true><<<1024, 512, 0, stream>>>(pred, tgt, part);
        norms_kernel<<<8, 256, 0, stream>>>(part, norms);
        loss_store_kernel<<<1024, 256, 0, stream>>>(part, norms, partial);
        finalize_kernel<<<1, 256, 0, stream>>>(partial, (float*)d_out);
    } else {
        float* gram    = ws;                           // 2 x 1024 x 1024 f32 = 8 MB
        float* partial = ws + (size_t)2 * 1024 * 1024;
        hipMemsetAsync(gram, 0, (size_t)2 * 1024 * 1024 * sizeof(float), stream);
        gram_kernel<false><<<1024, 512, 0, stream>>>(pred, tgt, gram);
        loss_atomic_kernel<<<1024, 256, 0, stream>>>(gram, partial);
        finalize_kernel<<<1, 256, 0, stream>>>(partial, (float*)d_out);
    }
}